// Round 5
// baseline (11.773 us; speedup 1.0000x reference)
//
#include <hip/hip_runtime.h>
#include <hip/hip_bf16.h>
#include <math.h>

// ROI pooling, faithful to the reference's quirky math:
//   cl = h/n steps along x (width/cc axis), rl = w/n steps along y (height/rr axis)
//   x1[i] = rne(x + i*cl), x2[i] = rne((x + i*cl) + cl)
//   y1[j] = rne(y + j*rl), y2[j] = rne((y + j*rl) + rl)
//   pooled[r, i, j, c] = max over rr in [y1,y2)∩[0,H), cc in [x1,x2)∩[0,W)
// Output: [R, 21, C]; n=1 -> bin 0, n=2 -> bins 1..4, n=4 -> bins 5..20,
// within a level bin = i*n + j (ix outer, jy inner).
//
// Round 4 -> 5: latency-chain probe. Same one-kernel structure as round 4
// (32 ROIs x 16 tasks x 1024 threads), but every task re-sliced as
// 8 column-slot accumulators x <=2 row iterations:
//   task 0..3 : n=1 bin, 16-quad channel group, 64 slices = 16 rows x 4 cols
//               (rstr=16, cstr=4; spans <=31 rows/31 cols -> covered by 32/32)
//   task 4..7 : n=2 bin, 16 slices = 8 rows x 2 cols (rstr=8, cstr=2; span<=16)
//   task 8..15: n=4 bins {2k,2k+1}, 8 slices = 8 rows x 1 col (span<=8)
// Dependent-load chain per accumulator: <=2 (was 4-5). Col guards are
// loop-invariant. Reductions: n=1 in-wave shfl + 1 barrier; n=2/n=4 one
// barrier + single-wave LDS scan (was 2 barriers).
// Bin spans proven: span = rne(a+len)-rne(a) <= len+1, and len=h/n or w/n
// with h,w in [8,30]: n=1 -> <=31, n=2 -> <=16, n=4 -> <=8 (integer).

#define HH 56
#define WW 56
#define NBINS 21  // 1 + 4 + 16

__device__ __forceinline__ float4 fmax4(float4 a, float4 b) {
    float4 r;
    r.x = fmaxf(a.x, b.x);
    r.y = fmaxf(a.y, b.y);
    r.z = fmaxf(a.z, b.z);
    r.w = fmaxf(a.w, b.w);
    return r;
}

__device__ __forceinline__ float4 shflxor4(float4 v, int mask) {
    float4 r;
    r.x = __shfl_xor(v.x, mask);
    r.y = __shfl_xor(v.y, mask);
    r.z = __shfl_xor(v.z, mask);
    r.w = __shfl_xor(v.w, mask);
    return r;
}

__global__ __launch_bounds__(1024, 4) void roi_pool_fused(
    const float4* __restrict__ feat4,  // [56,56,64] float4
    const float* __restrict__ rois,    // [R,4] (x,y,w,h)
    float4* __restrict__ out4)         // [R,21,64] float4
{
    const int bid  = blockIdx.x;
    const int r    = bid >> 4;
    const int task = bid & 15;
    const int t    = threadIdx.x;
    const int lane = t & 63;
    const int wv   = t >> 6;

    const float x = rois[r * 4 + 0];
    const float y = rois[r * 4 + 1];
    const float w = rois[r * 4 + 2];
    const float h = rois[r * 4 + 3];

    int n, i, j, q, sr, rstr, sc, cstr;
    if (task < 4) {            // n=1: 16 quads, 64 slices (16 rows x 4 cols)
        n = 1; i = 0; j = 0;
        q = (task << 4) | (t & 15);
        const int s = t >> 4;          // 0..63
        sr = s & 15; rstr = 16;
        sc = s >> 4; cstr = 4;         // 0..3
    } else if (task < 8) {     // n=2: 64 quads, 16 slices (8 rows x 2 cols)
        n = 2;
        const int b = task - 4; i = b >> 1; j = b & 1;
        q = lane;
        sr = wv & 7;  rstr = 8;
        sc = wv >> 3; cstr = 2;        // 0..1
    } else {                   // n=4: two bins/block, 8 slices (8 rows x 1 col)
        n = 4;
        const int b = ((task - 8) << 1) | (wv >> 3);   // 0..15
        i = b >> 2; j = b & 3;
        q = lane;
        sr = wv & 7; rstr = 8;
        sc = 0;      cstr = 1;
    }

    // Exact f32 ops (no FMA contraction) to match the numpy/JAX reference
    // bit-for-bit at round-to-nearest-even boundaries.
    const float cl = __fdiv_rn(h, (float)n);   // step along x (width)
    const float rl = __fdiv_rn(w, (float)n);   // step along y (height)

    const float ax = __fadd_rn(x, __fmul_rn((float)i, cl));
    const int   x1 = (int)rintf(ax);
    const int   x2 = (int)rintf(__fadd_rn(ax, cl));

    const float ay = __fadd_rn(y, __fmul_rn((float)j, rl));
    const int   y1 = (int)rintf(ay);
    const int   y2 = (int)rintf(__fadd_rn(ay, rl));

    const int r0 = max(y1, 0), r1 = min(y2, HH);
    const int c0 = max(x1, 0), c1 = min(x2, WW);

    const float4 NEG = make_float4(-INFINITY, -INFINITY, -INFINITY, -INFINITY);
    float4 m0 = NEG, m1 = NEG, m2 = NEG, m3 = NEG;
    float4 m4 = NEG, m5 = NEG, m6 = NEG, m7 = NEG;

    const float4* basel = feat4 + q;
    const int cc0 = c0 + sc;
    const int cc1 = cc0 + cstr;
    const int cc2 = cc1 + cstr;
    const int cc3 = cc2 + cstr;
    const int cc4 = cc3 + cstr;
    const int cc5 = cc4 + cstr;
    const int cc6 = cc5 + cstr;
    const int cc7 = cc6 + cstr;
    // <=2 row iterations; 8 loop-invariant col guards; chain length <=2 per acc.
    for (int rr = r0 + sr; rr < r1; rr += rstr) {
        const float4* rowp = basel + (size_t)(rr * WW) * 64;
        if (cc0 < c1) m0 = fmax4(m0, rowp[(size_t)cc0 * 64]);
        if (cc1 < c1) m1 = fmax4(m1, rowp[(size_t)cc1 * 64]);
        if (cc2 < c1) m2 = fmax4(m2, rowp[(size_t)cc2 * 64]);
        if (cc3 < c1) m3 = fmax4(m3, rowp[(size_t)cc3 * 64]);
        if (cc4 < c1) m4 = fmax4(m4, rowp[(size_t)cc4 * 64]);
        if (cc5 < c1) m5 = fmax4(m5, rowp[(size_t)cc5 * 64]);
        if (cc6 < c1) m6 = fmax4(m6, rowp[(size_t)cc6 * 64]);
        if (cc7 < c1) m7 = fmax4(m7, rowp[(size_t)cc7 * 64]);
    }
    float4 m = fmax4(fmax4(fmax4(m0, m1), fmax4(m2, m3)),
                     fmax4(fmax4(m4, m5), fmax4(m6, m7)));

    __shared__ float4 buf[16][64];  // 16 KB

    if (task < 4) {
        // wave holds 4 slices (lane>>4) x 16 quads (lane&15)
        m = fmax4(m, shflxor4(m, 16));
        m = fmax4(m, shflxor4(m, 32));
        if (lane < 16) buf[wv][lane] = m;      // [wave][quad]
        __syncthreads();
        if (t < 64) {
            const int p  = lane >> 4;           // 0..3
            const int ql = lane & 15;
            float4 v = fmax4(fmax4(buf[p][ql], buf[p + 4][ql]),
                             fmax4(buf[p + 8][ql], buf[p + 12][ql]));
            v = fmax4(v, shflxor4(v, 16));
            v = fmax4(v, shflxor4(v, 32));
            if (t < 16)
                out4[((size_t)r * NBINS + 0) * 64 + (task << 4) + t] = v;
        }
    } else if (task < 8) {
        buf[wv][lane] = m;
        __syncthreads();
        if (wv == 0) {
            float4 v = buf[0][lane];
            #pragma unroll
            for (int kk = 1; kk < 16; ++kk) v = fmax4(v, buf[kk][lane]);
            out4[((size_t)r * NBINS + 1 + (task - 4)) * 64 + lane] = v;
        }
    } else {
        buf[wv][lane] = m;
        __syncthreads();
        if ((wv & 7) == 0) {
            const int base = wv;                // 0 or 8
            float4 v = buf[base][lane];
            #pragma unroll
            for (int kk = 1; kk < 8; ++kk) v = fmax4(v, buf[base + kk][lane]);
            const int b = ((task - 8) << 1) | (wv >> 3);
            out4[((size_t)r * NBINS + 5 + b) * 64 + lane] = v;
        }
    }
}

extern "C" void kernel_launch(void* const* d_in, const int* in_sizes, int n_in,
                              void* d_out, int out_size, void* d_ws, size_t ws_size,
                              hipStream_t stream) {
    const float4* img  = (const float4*)d_in[0];  // [1,56,56,256] f32
    const float*  rois = (const float*)d_in[1];   // [1,32,4]
    float4* out = (float4*)d_out;                 // [1,32,21*256]

    const int R = in_sizes[1] / 4;                // 32

    roi_pool_fused<<<dim3(R * 16), dim3(1024), 0, stream>>>(img, rois, out);
}

// Round 6
// 10.672 us; speedup vs baseline: 1.1032x; 1.1032x over previous
//
#include <hip/hip_runtime.h>
#include <hip/hip_bf16.h>
#include <math.h>

// ROI pooling, faithful to the reference's quirky math:
//   cl = h/n steps along x (width/cc axis), rl = w/n steps along y (height/rr axis)
//   x1[i] = rne(x + i*cl), x2[i] = rne((x + i*cl) + cl)
//   y1[j] = rne(y + j*rl), y2[j] = rne((y + j*rl) + rl)
//   pooled[r, i, j, c] = max over rr in [y1,y2)∩[0,H), cc in [x1,x2)∩[0,W)
// Output: [R, 21, C]; n=1 -> bin 0, n=2 -> bins 1..4, n=4 -> bins 5..20,
// within a level bin = i*n + j (ix outer, jy inner).
//
// FINAL (revert to round-4 winner, 10.7 us). Round-5's chain-shortening probe
// (8 col slots x <=2 rows) REGRESSED to 11.8 us -> the kernel is not
// chain-latency-bound; ~9 us of the total is graph-replay/dispatch floor and
// kernel variants differ only within noise. Structure:
//   task 0..3 : n=1 bin, channel group task (64 ch), 64 cell-slices (8x8)
//   task 4..7 : n=2 bin task-4, all 256 ch, 16 cell-slices (4x4)
//   task 8..15: n=4 bins {2k, 2k+1}, half-block each, 8 slices (2x4)
// Every thread: <=4 rows x <=4 peeled col-slots = <=16 loads, no div/mod,
// no dynamic-index accumulators. Reduce: __shfl_xor in-wave + LDS tree.
// Grid = 32 ROIs x 16 tasks = 512 blocks x 16 waves = 8192 waves (= capacity).

#define HH 56
#define WW 56
#define NBINS 21  // 1 + 4 + 16

__device__ __forceinline__ float4 fmax4(float4 a, float4 b) {
    float4 r;
    r.x = fmaxf(a.x, b.x);
    r.y = fmaxf(a.y, b.y);
    r.z = fmaxf(a.z, b.z);
    r.w = fmaxf(a.w, b.w);
    return r;
}

__device__ __forceinline__ float4 shflxor4(float4 v, int mask) {
    float4 r;
    r.x = __shfl_xor(v.x, mask);
    r.y = __shfl_xor(v.y, mask);
    r.z = __shfl_xor(v.z, mask);
    r.w = __shfl_xor(v.w, mask);
    return r;
}

__global__ __launch_bounds__(1024, 8) void roi_pool_fused(
    const float4* __restrict__ feat4,  // [56,56,64] float4
    const float* __restrict__ rois,    // [R,4] (x,y,w,h)
    float4* __restrict__ out4)         // [R,21,64] float4
{
    const int bid  = blockIdx.x;
    const int r    = bid >> 4;
    const int task = bid & 15;
    const int t    = threadIdx.x;

    const float x = rois[r * 4 + 0];
    const float y = rois[r * 4 + 1];
    const float w = rois[r * 4 + 2];
    const float h = rois[r * 4 + 3];

    int n, i, j, q, sr, sc, rstr, cstr;
    if (task < 4) {            // n=1, channel-split: 16 quads, 64 slices (8x8)
        n = 1; i = 0; j = 0;
        q = (task << 4) | (t & 15);
        const int s = t >> 4;          // 0..63
        sr = s & 7;  sc = s >> 3;  rstr = 8; cstr = 8;
    } else if (task < 8) {     // n=2 bin: 64 quads, 16 slices (4x4)
        n = 2;
        const int b = task - 4; i = b >> 1; j = b & 1;
        q = t & 63;
        const int s = t >> 6;          // 0..15
        sr = s & 3;  sc = s >> 2;  rstr = 4; cstr = 4;
    } else {                   // n=4, two bins per block, 8 slices each (2x4)
        n = 4;
        const int s = t >> 6;          // 0..15
        const int b = ((task - 8) << 1) | (s >> 3);   // bin 0..15
        i = b >> 2; j = b & 3;
        q = t & 63;
        const int sh = s & 7;
        sr = sh & 1; sc = sh >> 1; rstr = 2; cstr = 4;
    }

    // Exact f32 ops (no FMA contraction) to match the numpy/JAX reference
    // bit-for-bit at round-to-nearest-even boundaries.
    const float cl = __fdiv_rn(h, (float)n);   // step along x (width)
    const float rl = __fdiv_rn(w, (float)n);   // step along y (height)

    const float ax = __fadd_rn(x, __fmul_rn((float)i, cl));
    const int   x1 = (int)rintf(ax);
    const int   x2 = (int)rintf(__fadd_rn(ax, cl));

    const float ay = __fadd_rn(y, __fmul_rn((float)j, rl));
    const int   y1 = (int)rintf(ay);
    const int   y2 = (int)rintf(__fadd_rn(ay, rl));

    const int r0 = max(y1, 0), r1 = min(y2, HH);
    const int c0 = max(x1, 0), c1 = min(x2, WW);

    const float4 NEG = make_float4(-INFINITY, -INFINITY, -INFINITY, -INFINITY);
    float4 m0 = NEG, m1 = NEG, m2 = NEG, m3 = NEG;

    const float4* basel = feat4 + q;
    const int cc0 = c0 + sc;
    const int cc1 = cc0 + cstr;
    const int cc2 = cc1 + cstr;
    const int cc3 = cc2 + cstr;
    // Loop-invariant col guards (hoisted by the compiler); rows <=4 iters.
    for (int rr = r0 + sr; rr < r1; rr += rstr) {
        const float4* rowp = basel + (size_t)(rr * WW) * 64;
        if (cc0 < c1) {
            m0 = fmax4(m0, rowp[(size_t)cc0 * 64]);
            if (cc1 < c1) {
                m1 = fmax4(m1, rowp[(size_t)cc1 * 64]);
                if (cc2 < c1) {
                    m2 = fmax4(m2, rowp[(size_t)cc2 * 64]);
                    if (cc3 < c1) {
                        m3 = fmax4(m3, rowp[(size_t)cc3 * 64]);
                    }
                }
            }
        }
    }
    float4 m = fmax4(fmax4(m0, m1), fmax4(m2, m3));

    __shared__ float4 buf[16][64];  // 16 KB
    const int lane = t & 63;
    const int wv   = t >> 6;

    if (task < 4) {
        // in-wave: each wave holds 4 slices (lane>>4) x 16 quads (lane&15)
        m = fmax4(m, shflxor4(m, 16));
        m = fmax4(m, shflxor4(m, 32));
        if (lane < 16) buf[wv][lane] = m;     // [wave][quad]
        __syncthreads();
        if (t < 64) {
            const int p  = lane >> 4;          // 0..3
            const int ql = lane & 15;
            float4 v = fmax4(fmax4(buf[p][ql], buf[p + 4][ql]),
                             fmax4(buf[p + 8][ql], buf[p + 12][ql]));
            v = fmax4(v, shflxor4(v, 16));
            v = fmax4(v, shflxor4(v, 32));
            if (t < 16)
                out4[((size_t)r * NBINS + 0) * 64 + (task << 4) + t] = v;
        }
    } else if (task < 8) {
        buf[wv][lane] = m;
        __syncthreads();
        if (wv < 4) {
            float4 v = fmax4(fmax4(buf[wv][lane], buf[wv + 4][lane]),
                             fmax4(buf[wv + 8][lane], buf[wv + 12][lane]));
            buf[wv][lane] = v;
        }
        __syncthreads();
        if (wv == 0) {
            float4 v = fmax4(fmax4(buf[0][lane], buf[1][lane]),
                             fmax4(buf[2][lane], buf[3][lane]));
            const int bin = 1 + (task - 4);
            out4[((size_t)r * NBINS + bin) * 64 + lane] = v;
        }
    } else {
        buf[wv][lane] = m;
        __syncthreads();
        const int half = wv >> 3;
        const int p    = wv & 7;
        if (p < 2) {
            const int base = (half << 3) + p;
            float4 v = fmax4(fmax4(buf[base][lane], buf[base + 2][lane]),
                             fmax4(buf[base + 4][lane], buf[base + 6][lane]));
            buf[base][lane] = v;
        }
        __syncthreads();
        if (p == 0) {
            const int base = half << 3;
            float4 v = fmax4(buf[base][lane], buf[base + 1][lane]);
            const int b = ((task - 8) << 1) | half;   // bin 0..15
            out4[((size_t)r * NBINS + 5 + b) * 64 + lane] = v;
        }
    }
}

extern "C" void kernel_launch(void* const* d_in, const int* in_sizes, int n_in,
                              void* d_out, int out_size, void* d_ws, size_t ws_size,
                              hipStream_t stream) {
    const float4* img  = (const float4*)d_in[0];  // [1,56,56,256] f32
    const float*  rois = (const float*)d_in[1];   // [1,32,4]
    float4* out = (float4*)d_out;                 // [1,32,21*256]

    const int R = in_sizes[1] / 4;                // 32

    roi_pool_fused<<<dim3(R * 16), dim3(1024), 0, stream>>>(img, rois, out);
}